// Round 2
// baseline (1157.576 us; speedup 1.0000x reference)
//
#include <hip/hip_runtime.h>

typedef __bf16 bf16;
typedef __bf16 bf16x8 __attribute__((ext_vector_type(8)));
typedef float floatx4 __attribute__((ext_vector_type(4)));

#define D_MODEL 2048
#define S_LEN   2048
#define BATCH   2
#define NHEADS  16
#define NKV     4
#define HD      128
#define KV_DIM  512
#define MROWS   (BATCH * S_LEN)   // 4096

// ---------------------------------------------------------------------------
// fp32 -> bf16 cast, 4 elems/thread
// ---------------------------------------------------------------------------
__global__ void cast_f32_bf16(const float* __restrict__ src, bf16* __restrict__ dst, int n)
{
  int i = (blockIdx.x * 256 + threadIdx.x) * 4;
  if (i < n) {
    float4 v = *(const float4*)(src + i);
    dst[i]     = (bf16)v.x;
    dst[i + 1] = (bf16)v.y;
    dst[i + 2] = (bf16)v.z;
    dst[i + 3] = (bf16)v.w;
  }
}

// ---------------------------------------------------------------------------
// NT GEMM: C[m,n] = sum_k A[m,k]*B[n,k] + bias[n].  A,B bf16; bias fp32;
// C bf16 (internal) or fp32 (final) per OUT_F32.
// 128x128 tile, BK=64, 256 thr = 4 waves 2x2, each wave 64x64 via 4x4 MFMAs.
// ---------------------------------------------------------------------------
template<bool OUT_F32>
__global__ __launch_bounds__(256, 2)
void gemm_bt_bias(const bf16* __restrict__ A, const bf16* __restrict__ B,
                  const float* __restrict__ bias, void* __restrict__ Cv,
                  int M, int N, int K)
{
  __shared__ bf16 As[128][72];   // row stride 144 B (16B multiple), breaks bank stride
  __shared__ bf16 Bs[128][72];
  const int tid  = threadIdx.x;
  const int lane = tid & 63, wave = tid >> 6;
  const int c15  = lane & 15, quad = lane >> 4;
  const int wm = (wave & 1) * 64, wn = (wave >> 1) * 64;
  const int m0 = blockIdx.y * 128, n0 = blockIdx.x * 128;

  floatx4 acc[4][4] = {};

  for (int k0 = 0; k0 < K; k0 += 64) {
#pragma unroll
    for (int it = 0; it < 4; ++it) {       // 128 rows x 8 chunks(16B) = 1024 slots
      int slot = it * 256 + tid;
      int row = slot >> 3, c8 = (slot & 7) * 8;
      *(uint4*)(&As[row][c8]) = *(const uint4*)(A + (long)(m0 + row) * K + k0 + c8);
      *(uint4*)(&Bs[row][c8]) = *(const uint4*)(B + (long)(n0 + row) * K + k0 + c8);
    }
    __syncthreads();
#pragma unroll
    for (int ks = 0; ks < 64; ks += 32) {
      bf16x8 af[4], bfr[4];
#pragma unroll
      for (int i = 0; i < 4; ++i) af[i]  = *(const bf16x8*)(&As[wm + i * 16 + c15][ks + quad * 8]);
#pragma unroll
      for (int j = 0; j < 4; ++j) bfr[j] = *(const bf16x8*)(&Bs[wn + j * 16 + c15][ks + quad * 8]);
#pragma unroll
      for (int i = 0; i < 4; ++i)
#pragma unroll
        for (int j = 0; j < 4; ++j)
          acc[i][j] = __builtin_amdgcn_mfma_f32_16x16x32_bf16(af[i], bfr[j], acc[i][j], 0, 0, 0);
    }
    __syncthreads();
  }
#pragma unroll
  for (int j = 0; j < 4; ++j) {
    int col = n0 + wn + j * 16 + c15;
    float bv = bias[col];
#pragma unroll
    for (int i = 0; i < 4; ++i)
#pragma unroll
      for (int r = 0; r < 4; ++r) {
        int row = m0 + wm + i * 16 + quad * 4 + r;
        float v = acc[i][j][r] + bv;
        if (OUT_F32) ((float*)Cv)[(long)row * N + col] = v;
        else         ((bf16*)Cv)[(long)row * N + col] = (bf16)v;
      }
  }
}

// ---------------------------------------------------------------------------
// RoPE on K (in place) and V (written transposed to Vt[b][kv][d][s]).
// Reference applies rotary to BOTH K and V (not Q).
// ---------------------------------------------------------------------------
__global__ void rope_kv(bf16* __restrict__ Kb, const bf16* __restrict__ Vb,
                        bf16* __restrict__ Vt)
{
  int idx = blockIdx.x * 256 + threadIdx.x;    // MROWS*NKV*64 threads
  int d   = idx & 63;
  int kv  = (idx >> 6) & 3;
  int row = idx >> 8;                          // 0..4095
  int s   = row & (S_LEN - 1);
  int b   = row >> 11;
  float inv_freq = expf(-(float)d * 0.14391156955f);   // ln(10000)/64
  float ang = (float)s * inv_freq;
  float cs = cosf(ang), sn = sinf(ang);
  long base = (long)row * KV_DIM + kv * HD + d;
  float k0 = (float)Kb[base], k1 = (float)Kb[base + 64];
  Kb[base]      = (bf16)(k0 * cs - k1 * sn);
  Kb[base + 64] = (bf16)(k1 * cs + k0 * sn);
  float v0 = (float)Vb[base], v1 = (float)Vb[base + 64];
  long tb = ((long)((b * NKV + kv) * HD + d)) * S_LEN + s;
  Vt[tb]              = (bf16)(v0 * cs - v1 * sn);
  Vt[tb + 64 * S_LEN] = (bf16)(v1 * cs + v0 * sn);
}

// ---------------------------------------------------------------------------
// Fused attention per (q-tile 128, b*h).  K in 64-wide tiles up to diagonal.
// Writes UNNORMALIZED P' = exp(s*scale - 10) as fp32 to attn output, bf16 to
// LDS for the PV MFMA; accumulates row sums Lg and O = (P'@V)/l (bf16 Ob).
// exp shift -10 guarantees no overflow; masked entries are exact 0.
// ---------------------------------------------------------------------------
__global__ __launch_bounds__(256, 2)
void attn_fused(const bf16* __restrict__ Qb, const bf16* __restrict__ Kb,
                const bf16* __restrict__ Vt, float* __restrict__ Pout,
                float* __restrict__ Lg, bf16* __restrict__ Ob)
{
  __shared__ bf16 Ks[64][136];    // [kpos][d]
  __shared__ bf16 Ps[128][72];    // [qrow][kpos]
  __shared__ bf16 Vts[128][72];   // [d][kpos]
  __shared__ float lred[2][128];
  __shared__ float lrun[128];

  const int tid  = threadIdx.x;
  const int lane = tid & 63, wave = tid >> 6;
  const int c15  = lane & 15, quad = lane >> 4;
  const int wm  = (wave & 1) * 64;
  const int wn2 = (wave >> 1) * 32;   // QK n-half (kpos)
  const int wn  = (wave >> 1) * 64;   // PV n-half (d)
  const int qt = blockIdx.x, bh = blockIdx.y;
  const int b = bh >> 4, h = bh & 15, kv = h >> 2;

  const bf16* Qg = Qb + (long)(b * S_LEN + qt * 128) * D_MODEL + h * HD;
  const bf16* Kg = Kb + (long)(b * S_LEN) * KV_DIM + kv * HD;
  const bf16* Vg = Vt + (long)((b * NKV + kv) * HD) * S_LEN;
  float* Pg = Pout + ((long)bh * S_LEN + qt * 128) * S_LEN;

  bf16x8 af_q[4][4];                         // Q fragments, registers only
#pragma unroll
  for (int i = 0; i < 4; ++i)
#pragma unroll
    for (int ks = 0; ks < 4; ++ks)
      af_q[i][ks] = *(const bf16x8*)(Qg + (long)(wm + i * 16 + c15) * D_MODEL + ks * 32 + quad * 8);

  if (tid < 128) lrun[tid] = 0.f;

  floatx4 acco[4][4] = {};
  const float scale = 0.08838834764831845f;  // 1/sqrt(128)
  const int nkt = (qt + 1) * 2;              // causal: 64-wide k-tiles up to diagonal

  for (int kt = 0; kt < nkt; ++kt) {
    __syncthreads();                          // prior tile's LDS reads done
#pragma unroll
    for (int it = 0; it < 4; ++it) {
      int slot = it * 256 + tid;
      { int row = slot >> 4, c8 = (slot & 15) * 8;   // Ks: 64 rows x 16 chunks
        *(uint4*)(&Ks[row][c8]) = *(const uint4*)(Kg + (long)(kt * 64 + row) * KV_DIM + c8); }
      { int row = slot >> 3, c8 = (slot & 7) * 8;    // Vts: 128 rows x 8 chunks
        *(uint4*)(&Vts[row][c8]) = *(const uint4*)(Vg + (long)row * S_LEN + kt * 64 + c8); }
    }
    __syncthreads();

    // S tile (128q x 64k) = Q @ K^T
    floatx4 acc[4][2] = {};
#pragma unroll
    for (int ks = 0; ks < 4; ++ks) {
      bf16x8 bfr[2];
#pragma unroll
      for (int j = 0; j < 2; ++j)
        bfr[j] = *(const bf16x8*)(&Ks[wn2 + j * 16 + c15][ks * 32 + quad * 8]);
#pragma unroll
      for (int i = 0; i < 4; ++i)
#pragma unroll
        for (int j = 0; j < 2; ++j)
          acc[i][j] = __builtin_amdgcn_mfma_f32_16x16x32_bf16(af_q[i][ks], bfr[j], acc[i][j], 0, 0, 0);
    }

    // P' + row-sum partials; store to LDS (PV A-operand) and global attn (fp32)
#pragma unroll
    for (int i = 0; i < 4; ++i) {
      float ps[4] = {0.f, 0.f, 0.f, 0.f};
#pragma unroll
      for (int j = 0; j < 2; ++j) {
        int colg = kt * 64 + wn2 + j * 16 + c15;
#pragma unroll
        for (int r = 0; r < 4; ++r) {
          int rowl = wm + i * 16 + quad * 4 + r;
          int rowg = qt * 128 + rowl;
          float p = (colg <= rowg) ? __expf(acc[i][j][r] * scale - 10.f) : 0.f;
          ps[r] += p;
          Ps[rowl][wn2 + j * 16 + c15] = (bf16)p;
          Pg[(long)rowl * S_LEN + colg] = p;
        }
      }
#pragma unroll
      for (int r = 0; r < 4; ++r) {          // reduce over the 16 col-lanes
        float v = ps[r];
        v += __shfl_xor(v, 1); v += __shfl_xor(v, 2);
        v += __shfl_xor(v, 4); v += __shfl_xor(v, 8);
        if (c15 == 0) lred[wave >> 1][wm + i * 16 + quad * 4 + r] = v;
      }
    }
    __syncthreads();                          // Ps + lred visible everywhere
    if (tid < 128) lrun[tid] += lred[0][tid] + lred[1][tid];

    // O += P' @ V   (O tile 128q x 128d, k-dim 64)
#pragma unroll
    for (int ks = 0; ks < 2; ++ks) {
      bf16x8 paf[4], vbf[4];
#pragma unroll
      for (int i = 0; i < 4; ++i) paf[i] = *(const bf16x8*)(&Ps[wm + i * 16 + c15][ks * 32 + quad * 8]);
#pragma unroll
      for (int j = 0; j < 4; ++j) vbf[j] = *(const bf16x8*)(&Vts[wn + j * 16 + c15][ks * 32 + quad * 8]);
#pragma unroll
      for (int i = 0; i < 4; ++i)
#pragma unroll
        for (int j = 0; j < 4; ++j)
          acco[i][j] = __builtin_amdgcn_mfma_f32_16x16x32_bf16(paf[i], vbf[j], acco[i][j], 0, 0, 0);
    }
  }
  __syncthreads();                            // lrun final

  bf16* Og = Ob + (long)(b * S_LEN + qt * 128) * D_MODEL + h * HD;
#pragma unroll
  for (int i = 0; i < 4; ++i)
#pragma unroll
    for (int r = 0; r < 4; ++r) {
      int rowl = wm + i * 16 + quad * 4 + r;
      float invl = 1.f / lrun[rowl];
#pragma unroll
      for (int j = 0; j < 4; ++j)
        Og[(long)rowl * D_MODEL + wn + j * 16 + c15] = (bf16)(acco[i][j][r] * invl);
    }
  if (tid < 128) Lg[(long)bh * S_LEN + qt * 128 + tid] = lrun[tid];
}

// ---------------------------------------------------------------------------
// Normalize attn rows by 1/l (fp32); zero-fill above the diagonal (covers the
// never-written poisoned region).  One block per row, 8 floats per thread.
// ---------------------------------------------------------------------------
__global__ void attn_norm(float* __restrict__ P, const float* __restrict__ Lg)
{
  long row = blockIdx.x;                       // bh*2048 + s
  int s = (int)(row & (S_LEN - 1));
  float invl = 1.f / Lg[row];
  float* p = P + row * S_LEN;
  int c0 = threadIdx.x * 8;
  float4 a, bq;
  if (c0 > s) {
    a = make_float4(0.f, 0.f, 0.f, 0.f);
    bq = a;
  } else {
    a  = *(const float4*)(p + c0);
    bq = *(const float4*)(p + c0 + 4);
    a.x = (c0 + 0 <= s) ? a.x * invl : 0.f;
    a.y = (c0 + 1 <= s) ? a.y * invl : 0.f;
    a.z = (c0 + 2 <= s) ? a.z * invl : 0.f;
    a.w = (c0 + 3 <= s) ? a.w * invl : 0.f;
    bq.x = (c0 + 4 <= s) ? bq.x * invl : 0.f;
    bq.y = (c0 + 5 <= s) ? bq.y * invl : 0.f;
    bq.z = (c0 + 6 <= s) ? bq.z * invl : 0.f;
    bq.w = (c0 + 7 <= s) ? bq.w * invl : 0.f;
  }
  *(float4*)(p + c0)     = a;
  *(float4*)(p + c0 + 4) = bq;
}

// ---------------------------------------------------------------------------
extern "C" void kernel_launch(void* const* d_in, const int* in_sizes, int n_in,
                              void* d_out, int out_size, void* d_ws, size_t ws_size,
                              hipStream_t stream)
{
  const float* query = (const float*)d_in[0];
  // d_in[1] = attention_mask: deterministic causal tril — not needed
  const float* Wq = (const float*)d_in[2];
  const float* bq = (const float*)d_in[3];
  const float* Wk = (const float*)d_in[4];
  const float* bk = (const float*)d_in[5];
  const float* Wv = (const float*)d_in[6];
  const float* bv = (const float*)d_in[7];
  const float* Wo = (const float*)d_in[8];
  const float* bo = (const float*)d_in[9];

  float* out  = (float*)d_out;                              // (4096, 2048) fp32
  float* attn = (float*)d_out + (long)MROWS * D_MODEL;      // (32*2048, 2048) fp32

  char* ws = (char*)d_ws;
  bf16* Qb   = (bf16*)(ws);                 // 16 MB  (4096 x 2048)
  bf16* Kb   = (bf16*)(ws + (17l << 20));   //  4 MB  (4096 x 512)
  bf16* Vb   = (bf16*)(ws + (22l << 20));   //  4 MB  (4096 x 512)
  bf16* Vt   = (bf16*)(ws + (27l << 20));   //  4 MB  (2*4*128 x 2048)
  bf16* Ob   = (bf16*)(ws + (32l << 20));   // 16 MB  (4096 x 2048)
  float* Lg  = (float*)(ws + (49l << 20));  // 512 KB (2*16*2048)
  bf16* qbf  = (bf16*)(ws + (50l << 20));   // 16 MB  (4096 x 2048)
  bf16* wqbf = (bf16*)(ws + (67l << 20));   //  8 MB  (2048 x 2048)
  bf16* wkbf = (bf16*)(ws + (76l << 20));   //  2 MB  (512 x 2048)
  bf16* wvbf = (bf16*)(ws + (79l << 20));   //  2 MB  (512 x 2048)
  bf16* wobf = (bf16*)(ws + (82l << 20));   //  8 MB  (2048 x 2048)

  dim3 blk(256);
  cast_f32_bf16<<<dim3(MROWS * D_MODEL / 1024), blk, 0, stream>>>(query, qbf, MROWS * D_MODEL);
  cast_f32_bf16<<<dim3(D_MODEL * D_MODEL / 1024), blk, 0, stream>>>(Wq, wqbf, D_MODEL * D_MODEL);
  cast_f32_bf16<<<dim3(KV_DIM * D_MODEL / 1024), blk, 0, stream>>>(Wk, wkbf, KV_DIM * D_MODEL);
  cast_f32_bf16<<<dim3(KV_DIM * D_MODEL / 1024), blk, 0, stream>>>(Wv, wvbf, KV_DIM * D_MODEL);
  cast_f32_bf16<<<dim3(D_MODEL * D_MODEL / 1024), blk, 0, stream>>>(Wo, wobf, D_MODEL * D_MODEL);

  gemm_bt_bias<false><<<dim3(D_MODEL / 128, MROWS / 128), blk, 0, stream>>>(qbf, wqbf, bq, Qb, MROWS, D_MODEL, D_MODEL);
  gemm_bt_bias<false><<<dim3(KV_DIM / 128, MROWS / 128), blk, 0, stream>>>(qbf, wkbf, bk, Kb, MROWS, KV_DIM, D_MODEL);
  gemm_bt_bias<false><<<dim3(KV_DIM / 128, MROWS / 128), blk, 0, stream>>>(qbf, wvbf, bv, Vb, MROWS, KV_DIM, D_MODEL);
  rope_kv<<<dim3(MROWS * NKV * 64 / 256), blk, 0, stream>>>(Kb, Vb, Vt);
  attn_fused<<<dim3(S_LEN / 128, BATCH * NHEADS), blk, 0, stream>>>(Qb, Kb, Vt, attn, Lg, Ob);
  attn_norm<<<dim3(BATCH * NHEADS * S_LEN), blk, 0, stream>>>(attn, Lg);
  gemm_bt_bias<true><<<dim3(D_MODEL / 128, MROWS / 128), blk, 0, stream>>>(Ob, wobf, bo, out, MROWS, D_MODEL, D_MODEL);
}